// Round 1
// baseline (18.464 us; speedup 1.0000x reference)
//
#include <hip/hip_runtime.h>

#define D_DIM 32768
#define NT 64
#define NKEYS 120

__constant__ int c_feat_idx[NKEYS] = {
    557, 581, 553, 551, 92, 554, 579, 570, 573, 577,
    565, 286, 555, 549, 13, 550, 63, 580, 556, 564,
    0, 576, 567, 552, 578, 588, 597, 566, 571, 44,
    572, 574, 14, 582, 381, 594, 4, 593, 218, 25,
    84, 592, 3, 591, 547, 561, 562, 548, 319, 596,
    558, 563, 87, 65, 599, 17, 88, 2, 49, 309,
    6, 81, 15, 590, 589, 43, 273, 420, 546, 568,
    400, 277, 202, 287, 434, 435, 423, 431, 301, 417,
    412, 205, 179, 327, 176, 442, 172, 450, 391, 163,
    154, 480, 485, 490, 491, 498, 503, 507, 509, 452,
    239, 388, 219, 303, 292, 310, 316, 320, 322, 324,
    326, 330, 336, 263, 262, 339, 340, 256, 345, 347};

__device__ __forceinline__ int level_idx(float x) {
    // replicate: clip(x,-5,5); round(((x+5)/10)*2047) half-to-even; clip 0..2047
    x = fminf(fmaxf(x, -5.0f), 5.0f);
    float v = (x + 5.0f) / 10.0f * 2047.0f;
    int i = (int)rintf(v);
    return min(max(i, 0), 2047);
}

__global__ __launch_bounds__(256) void hdc_encode_kernel(
    const float* __restrict__ input,
    const float* __restrict__ feat,
    const float* __restrict__ Wx,
    const float* __restrict__ Wy,
    const float* __restrict__ Wz,
    const float* __restrict__ Wt,
    const float* __restrict__ keys,
    float* __restrict__ out)
{
    __shared__ int s_idx[4][NT];      // ix, iy, iz, it
    __shared__ int s_fidx[NKEYS];
    __shared__ unsigned sh_sign[4][64];
    __shared__ unsigned sh_any3[4][64];
    __shared__ float    sh_f[4][64];

    const int tid = threadIdx.x;

    if (tid < NT) {
        float x = input[tid * 4 + 1];
        float y = input[tid * 4 + 2];
        float z = input[tid * 4 + 3];
        s_idx[0][tid] = level_idx(x);
        s_idx[1][tid] = level_idx(y);
        s_idx[2][tid] = level_idx(z);
        // t index: round((t/64)*63) half-to-even, clip 0..63
        float tv = (float)tid;
        int it = (int)rintf(tv / 64.0f * 63.0f);
        s_idx[3][tid] = min(max(it, 0), NT - 1);
    }
    if (tid >= 64 && tid < 64 + NKEYS) {
        int j = tid - 64;
        float fv = feat[c_feat_idx[j]];
        fv = fminf(fmaxf(fv, -1.0f), 1.0f);
        // round(((fv+1)*0.5)*32768) half-to-even
        s_fidx[j] = (int)rintf((fv + 1.0f) * 0.5f * 32768.0f);
    }
    __syncthreads();

    const int slice = tid >> 6;       // 0..3
    const int lane  = tid & 63;
    const int d = (blockIdx.x << 6) + lane;

    // --- sample part: 16 timestamps per slice ---
    unsigned signacc = 0u;
    unsigned any3 = 0u;
    const int t0 = slice * 16;
#pragma unroll
    for (int k = 0; k < 16; ++k) {
        int t = t0 + k;
        float x = Wx[((unsigned)s_idx[0][t] << 15) + d];
        float y = Wy[((unsigned)s_idx[1][t] << 15) + d];
        float z = Wz[((unsigned)s_idx[2][t] << 15) + d];
        float w = Wt[((unsigned)s_idx[3][t] << 15) + d];
        float s = x + y + z;                  // in {±1, ±3} exactly
        float v = s * w;
        signacc ^= __float_as_uint(v);        // accumulate sign bit
        any3 |= (fabsf(s) > 2.0f) ? 1u : 0u;
    }
    signacc &= 0x80000000u;

    // --- feature part: 30 keys per slice ---
    float fpart = 0.0f;
    const int j0 = slice * 30;
#pragma unroll
    for (int k = 0; k < 30; ++k) {
        int j = j0 + k;
        float kv = keys[(j << 15) + d];
        fpart += (d < s_fidx[j]) ? kv : -kv;
    }

    sh_sign[slice][lane] = signacc;
    sh_any3[slice][lane] = any3;
    sh_f[slice][lane]    = fpart;
    __syncthreads();

    if (slice == 0) {
        unsigned sg = sh_sign[0][lane] ^ sh_sign[1][lane] ^ sh_sign[2][lane] ^ sh_sign[3][lane];
        unsigned a3 = sh_any3[0][lane] | sh_any3[1][lane] | sh_any3[2][lane] | sh_any3[3][lane];
        float f = sh_f[0][lane] + sh_f[1][lane] + sh_f[2][lane] + sh_f[3][lane];
        bool neg = (sg & 0x80000000u) != 0u;
        float o;
        if (f >= 0.0f) {
            o = neg ? -1.0f : 1.0f;           // sign(sample_hv)
        } else {
            o = (neg && a3) ? 1.0f : -1.0f;   // f <= -2 branch
        }
        out[d] = o;
    }
}

extern "C" void kernel_launch(void* const* d_in, const int* in_sizes, int n_in,
                              void* d_out, int out_size, void* d_ws, size_t ws_size,
                              hipStream_t stream) {
    const float* input = (const float*)d_in[0];
    const float* feat  = (const float*)d_in[1];
    const float* Wx    = (const float*)d_in[2];
    const float* Wy    = (const float*)d_in[3];
    const float* Wz    = (const float*)d_in[4];
    const float* Wt    = (const float*)d_in[5];
    const float* keys  = (const float*)d_in[6];
    float* out = (float*)d_out;

    dim3 grid(D_DIM / 64);   // 512 blocks, 64 dims each
    dim3 block(256);
    hipLaunchKernelGGL(hdc_encode_kernel, grid, block, 0, stream,
                       input, feat, Wx, Wy, Wz, Wt, Wt == nullptr ? nullptr : keys, out);
}

// Round 2
// 13.790 us; speedup vs baseline: 1.3389x; 1.3389x over previous
//
#include <hip/hip_runtime.h>

#define D_DIM 32768
#define NT 64
#define NKEYS 120
#define TPB 1024
#define DB 128      // dims per block
#define NW 16       // waves per block

__constant__ int c_feat_idx[NKEYS] = {
    557, 581, 553, 551, 92, 554, 579, 570, 573, 577,
    565, 286, 555, 549, 13, 550, 63, 580, 556, 564,
    0, 576, 567, 552, 578, 588, 597, 566, 571, 44,
    572, 574, 14, 582, 381, 594, 4, 593, 218, 25,
    84, 592, 3, 591, 547, 561, 562, 548, 319, 596,
    558, 563, 87, 65, 599, 17, 88, 2, 49, 309,
    6, 81, 15, 590, 589, 43, 273, 420, 546, 568,
    400, 277, 202, 287, 434, 435, 423, 431, 301, 417,
    412, 205, 179, 327, 176, 442, 172, 450, 391, 163,
    154, 480, 485, 490, 491, 498, 503, 507, 509, 452,
    239, 388, 219, 303, 292, 310, 316, 320, 322, 324,
    326, 330, 336, 263, 262, 339, 340, 256, 345, 347};

__device__ __forceinline__ int level_idx(float x) {
    // replicate: clip(x,-5,5); round(((x+5)/10)*2047) half-to-even; clip 0..2047
    x = fminf(fmaxf(x, -5.0f), 5.0f);
    float v = (x + 5.0f) / 10.0f * 2047.0f;
    int i = (int)rintf(v);
    return min(max(i, 0), 2047);
}

__global__ __launch_bounds__(TPB) void hdc_encode_kernel(
    const float* __restrict__ input,
    const float* __restrict__ feat,
    const float* __restrict__ Wx,
    const float* __restrict__ Wy,
    const float* __restrict__ Wz,
    const float* __restrict__ Wt,
    const float* __restrict__ keys,
    float* __restrict__ out)
{
    __shared__ int   s_idx[4][NT];     // ix, iy, iz, it
    __shared__ int   s_fidx[NKEYS];
    __shared__ int   s_meta[NW][DB];   // bit0..7: sign count, bit8+: any3 count
    __shared__ float s_f[NW][DB];

    const int tid = threadIdx.x;

    if (tid < NT) {
        float x = input[tid * 4 + 1];
        float y = input[tid * 4 + 2];
        float z = input[tid * 4 + 3];
        s_idx[0][tid] = level_idx(x);
        s_idx[1][tid] = level_idx(y);
        s_idx[2][tid] = level_idx(z);
        float tv = (float)tid;
        int it = (int)rintf(tv / 64.0f * 63.0f);
        s_idx[3][tid] = min(max(it, 0), NT - 1);
    } else if (tid < NT + NKEYS) {
        int j = tid - NT;
        float fv = feat[c_feat_idx[j]];
        fv = fminf(fmaxf(fv, -1.0f), 1.0f);
        s_fidx[j] = (int)rintf((fv + 1.0f) * 0.5f * 32768.0f);
    }
    __syncthreads();

    const int wave = __builtin_amdgcn_readfirstlane(tid >> 6);  // 0..15, wave-uniform SGPR
    const int lane = tid & 63;
    const int d0 = blockIdx.x * DB + lane * 2;   // this lane's two dims: d0, d0+1

    // --- sample part: 4 timestamps per wave-slice ---
    unsigned sg0 = 0u, sg1 = 0u;
    int a30 = 0, a31 = 0;
    const int t0 = wave * 4;
#pragma unroll
    for (int k = 0; k < 4; ++k) {
        int t = t0 + k;
        int ix = __builtin_amdgcn_readfirstlane(s_idx[0][t]);
        int iy = __builtin_amdgcn_readfirstlane(s_idx[1][t]);
        int iz = __builtin_amdgcn_readfirstlane(s_idx[2][t]);
        int it = __builtin_amdgcn_readfirstlane(s_idx[3][t]);
        float2 x = *(const float2*)(Wx + ((size_t)ix << 15) + d0);
        float2 y = *(const float2*)(Wy + ((size_t)iy << 15) + d0);
        float2 z = *(const float2*)(Wz + ((size_t)iz << 15) + d0);
        float2 w = *(const float2*)(Wt + ((size_t)it << 15) + d0);
        float sA = x.x + y.x + z.x;          // in {±1, ±3} exactly
        float sB = x.y + y.y + z.y;
        sg0 ^= __float_as_uint(sA * w.x);
        sg1 ^= __float_as_uint(sB * w.y);
        a30 |= (fabsf(sA) > 2.0f) ? 1 : 0;
        a31 |= (fabsf(sB) > 2.0f) ? 1 : 0;
    }

    // --- feature part: 8 keys for waves 0..7, 7 keys for waves 8..15 ---
    float f0 = 0.0f, f1 = 0.0f;
    if (wave < 8) {
        const int j0 = wave * 8;
#pragma unroll
        for (int k = 0; k < 8; ++k) {
            int j = j0 + k;
            int fx = __builtin_amdgcn_readfirstlane(s_fidx[j]);
            float2 kv = *(const float2*)(keys + ((size_t)j << 15) + d0);
            f0 += (d0 < fx) ? kv.x : -kv.x;
            f1 += (d0 + 1 < fx) ? kv.y : -kv.y;
        }
    } else {
        const int j0 = 64 + (wave - 8) * 7;
#pragma unroll
        for (int k = 0; k < 7; ++k) {
            int j = j0 + k;
            int fx = __builtin_amdgcn_readfirstlane(s_fidx[j]);
            float2 kv = *(const float2*)(keys + ((size_t)j << 15) + d0);
            f0 += (d0 < fx) ? kv.x : -kv.x;
            f1 += (d0 + 1 < fx) ? kv.y : -kv.y;
        }
    }

    const int col = lane * 2;
    s_meta[wave][col]     = (int)(sg0 >> 31) | (a30 << 8);
    s_meta[wave][col + 1] = (int)(sg1 >> 31) | (a31 << 8);
    s_f[wave][col]     = f0;
    s_f[wave][col + 1] = f1;
    __syncthreads();

    if (tid < DB) {
        int msum = 0;
        float f = 0.0f;
#pragma unroll
        for (int w2 = 0; w2 < NW; ++w2) {
            msum += s_meta[w2][tid];
            f    += s_f[w2][tid];
        }
        bool neg  = (msum & 1) != 0;          // parity of sign bits = sign of product
        bool any3 = (msum & 0xFF00) != 0;     // any |x+y+z| == 3
        float o;
        if (f >= 0.0f) o = neg ? -1.0f : 1.0f;
        else           o = (neg && any3) ? 1.0f : -1.0f;
        out[blockIdx.x * DB + tid] = o;
    }
}

extern "C" void kernel_launch(void* const* d_in, const int* in_sizes, int n_in,
                              void* d_out, int out_size, void* d_ws, size_t ws_size,
                              hipStream_t stream) {
    const float* input = (const float*)d_in[0];
    const float* feat  = (const float*)d_in[1];
    const float* Wx    = (const float*)d_in[2];
    const float* Wy    = (const float*)d_in[3];
    const float* Wz    = (const float*)d_in[4];
    const float* Wt    = (const float*)d_in[5];
    const float* keys  = (const float*)d_in[6];
    float* out = (float*)d_out;

    dim3 grid(D_DIM / DB);   // 256 blocks -> one per CU
    dim3 block(TPB);
    hipLaunchKernelGGL(hdc_encode_kernel, grid, block, 0, stream,
                       input, feat, Wx, Wy, Wz, Wt, keys, out);
}